// Round 1
// baseline (2225.740 us; speedup 1.0000x reference)
//
#include <hip/hip_runtime.h>

// FlowNetC correlation on MI355X.
// out[b, d, h, w] = (1/256) * sum_c in1[b,c,h,w] * in2[b,c,h+dy,w+dx]
//   d = iy*21 + ix, dy = 2*iy - 20, dx = 2*ix - 20, zero outside bounds.
// B=8 C=256 H=64 W=96, out = [8, 441, 64, 96] fp32.

#define B_   8
#define C_   256
#define H_   64
#define W_   96
#define NIY  21
#define NIX  21
#define EW   136   // e = w + 2*ix in [0, 95 + 40] -> 136 values
#define HT   7     // h rows per block
#define CK   8     // channel chunk staged in LDS
// padded LDS strides (bank-conflict softening: 100%32=4, 140%32=12)
#define SAW  100
#define SBW  140

__global__ __launch_bounds__(256) void corr_kernel(
    const float* __restrict__ in1,
    const float* __restrict__ in2,
    float* __restrict__ out) {

  const int iy = blockIdx.x;        // 0..20
  const int ht = blockIdx.y;        // 0..9  (ceil(64/7))
  const int b  = blockIdx.z;        // 0..7
  const int h0 = ht * HT;
  const int dy = 2 * iy - 20;

  __shared__ float sA[CK][HT][SAW];
  __shared__ float sB[CK][HT][SBW];

  const int t = threadIdx.x;
  // compute-role decomposition (252 active threads)
  const int hl = t / 36;            // 0..6
  const int rr = t % 36;
  const int jg = rr / 12;           // 0..2 -> ix0 = jg*7
  const int wg = rr % 12;           // 0..11 -> w0 = wg*8
  const int w0  = wg * 8;
  const int ix0 = jg * 7;
  const int e0  = w0 + 2 * ix0;     // B-window base, 20 floats wide (max 116+19=135)

  float acc[7][8];
#pragma unroll
  for (int j = 0; j < 7; ++j)
#pragma unroll
    for (int q = 0; q < 8; ++q) acc[j][q] = 0.0f;

  for (int c0 = 0; c0 < C_; c0 += CK) {
    __syncthreads();  // previous compute done before overwriting LDS
    // stage in1 chunk: [CK][HT][96]
    for (int i = t; i < CK * HT * W_; i += 256) {
      int c   = i / (HT * W_);
      int rem = i % (HT * W_);
      int hh  = rem / W_;
      int w   = rem % W_;
      int h   = h0 + hh;
      float v = 0.0f;
      if (h < H_) v = in1[(((size_t)b * C_ + c0 + c) * H_ + h) * W_ + w];
      sA[c][hh][w] = v;
    }
    // stage padded in2 chunk: [CK][HT][136], row h+dy, w2 = e - 20
    for (int i = t; i < CK * HT * EW; i += 256) {
      int c   = i / (HT * EW);
      int rem = i % (HT * EW);
      int hh  = rem / EW;
      int e   = rem % EW;
      int h2  = h0 + hh + dy;
      int w2  = e - 20;
      float v = 0.0f;
      if (h2 >= 0 && h2 < H_ && w2 >= 0 && w2 < W_)
        v = in2[(((size_t)b * C_ + c0 + c) * H_ + h2) * W_ + w2];
      sB[c][hh][e] = v;
    }
    __syncthreads();

    if (t < 252) {
#pragma unroll
      for (int c = 0; c < CK; ++c) {
        float a[8], bb[20];
#pragma unroll
        for (int q = 0; q < 8; ++q)  a[q]  = sA[c][hl][w0 + q];
#pragma unroll
        for (int q = 0; q < 20; ++q) bb[q] = sB[c][hl][e0 + q];
#pragma unroll
        for (int j = 0; j < 7; ++j)
#pragma unroll
          for (int q = 0; q < 8; ++q)
            acc[j][q] += a[q] * bb[2 * j + q];  // e = w0+q + 2*(ix0+j)
      }
    }
  }

  if (t < 252) {
    const int h = h0 + hl;
    if (h < H_) {
#pragma unroll
      for (int j = 0; j < 7; ++j) {
        const int d = iy * NIX + ix0 + j;
        const size_t base = (((size_t)b * (NIY * NIX) + d) * H_ + h) * W_ + w0;
#pragma unroll
        for (int q = 0; q < 8; ++q)
          out[base + q] = acc[j][q] * (1.0f / 256.0f);
      }
    }
  }
}

extern "C" void kernel_launch(void* const* d_in, const int* in_sizes, int n_in,
                              void* d_out, int out_size, void* d_ws, size_t ws_size,
                              hipStream_t stream) {
  const float* in1 = (const float*)d_in[0];
  const float* in2 = (const float*)d_in[1];
  float* out = (float*)d_out;
  dim3 grid(NIY, (H_ + HT - 1) / HT, B_);  // (21, 10, 8)
  corr_kernel<<<grid, 256, 0, stream>>>(in1, in2, out);
}

// Round 2
// 505.357 us; speedup vs baseline: 4.4043x; 4.4043x over previous
//
#include <hip/hip_runtime.h>

// FlowNetC correlation, MFMA bf16 banded-GEMM formulation.
// out[b, iy*21+ix, h, w] = (1/256) sum_c in1[b,c,h,w] * in2[b,c,h+dy,w+dx]
//   dy = 2*iy-20, dx = 2*ix-20, zero-padded outside the image.
// Parity split: w = 2u+r, w' = 2v+r, v = u+ix-10:
//   out[ix, 2u+r] = sum_c A_r[c,u] * B_r[c,v]   (banded Gram, |v-u| <= 10)
// Phase 1 packs A (in1) and B (in2) as bf16 into d_ws, c-major rows padded to
// 264 (528 B: 16B-aligned b128 reads, row stride 132 dw = 4 mod 32 -> 2-way
// bank aliasing = free). B packed over q = v+16 in [0,80), zeros where w' OOB.
// Phase 2: block=(b,h), 6 waves = (r, u-tile), 21-dy loop, reg-prefetch
// pipeline, 3 v-tile accumulators per wave via mfma_f32_16x16x32_bf16.

#define B_    8
#define C_    256
#define H_    64
#define W_    96
#define CP    264          // padded c (row = 528 B)
#define NU    48           // u per parity
#define NQ    80           // q slots per parity (v in [-16,64))
#define WS1_BH (2 * NU * CP)           // 25344 elems per (b,h)
#define WS2_BH (2 * NQ * CP)           // 42240 elems per (b,h)

typedef __bf16 bf16x8 __attribute__((ext_vector_type(8)));
typedef float  f32x4  __attribute__((ext_vector_type(4)));

// ---------------- Phase 1: pack fp32 -> bf16 (transpose + pad + parity split)
__global__ __launch_bounds__(256) void pack_kernel(
    const float* __restrict__ in1, const float* __restrict__ in2,
    __bf16* __restrict__ ws1, __bf16* __restrict__ ws2) {
  const int b = blockIdx.x >> 6;
  const int h = blockIdx.x & 63;
  const int t = threadIdx.x;
  __shared__ float sT[64][101];   // 64 c x 96 w (pad 101: 2-way free)

  __bf16* dst1 = ws1 + (size_t)(b * 64 + h) * WS1_BH;
  for (int c0 = 0; c0 < C_; c0 += 64) {
    __syncthreads();
    for (int idx = t; idx < 1536; idx += 256) {          // 64c x 24 float4
      int cc = idx / 24, w4 = idx % 24;
      float4 v = ((const float4*)(in1 + (((size_t)(b * C_ + c0 + cc) * H_ + h) * W_)))[w4];
      sT[cc][w4 * 4 + 0] = v.x; sT[cc][w4 * 4 + 1] = v.y;
      sT[cc][w4 * 4 + 2] = v.z; sT[cc][w4 * 4 + 3] = v.w;
    }
    __syncthreads();
    const int cc = t & 63;
#pragma unroll
    for (int p = 0; p < 24; ++p) {                       // 96 (r,u) rows / 4
      int ru = (t >> 6) + p * 4;                         // 0..95
      int r = ru / NU, u = ru % NU;
      dst1[ru * CP + c0 + cc] = (__bf16)sT[cc][2 * u + r];
    }
  }

  __bf16* dst2 = ws2 + (size_t)(b * 64 + h) * WS2_BH;
  for (int c0 = 0; c0 < C_; c0 += 64) {
    __syncthreads();
    for (int idx = t; idx < 1536; idx += 256) {
      int cc = idx / 24, w4 = idx % 24;
      float4 v = ((const float4*)(in2 + (((size_t)(b * C_ + c0 + cc) * H_ + h) * W_)))[w4];
      sT[cc][w4 * 4 + 0] = v.x; sT[cc][w4 * 4 + 1] = v.y;
      sT[cc][w4 * 4 + 2] = v.z; sT[cc][w4 * 4 + 3] = v.w;
    }
    __syncthreads();
    const int cc = t & 63;
#pragma unroll
    for (int p = 0; p < 40; ++p) {                       // 160 (r,q) rows / 4
      int ru = (t >> 6) + p * 4;                         // 0..159
      int r = ru / NQ, q = ru % NQ;
      int w2 = 2 * q + r - 32;                           // w' for this q
      float v = (w2 >= 0 && w2 < W_) ? sT[cc][w2] : 0.0f;
      dst2[ru * CP + c0 + cc] = (__bf16)v;
    }
  }
}

// ---------------- Phase 2: MFMA band-GEMM over 21 dy
__global__ __launch_bounds__(384) void corr_mfma(
    const __bf16* __restrict__ ws1, const __bf16* __restrict__ ws2,
    float* __restrict__ out) {
  const int b = blockIdx.x >> 6;
  const int h = blockIdx.x & 63;
  const int t = threadIdx.x;
  const int wave = t >> 6, lane = t & 63;
  const int rr = wave & 1;                // parity
  const int u0 = (wave >> 1) << 4;        // u-tile base: 0,16,32
  const int col = lane & 15, quad = lane >> 4;

  __shared__ __bf16 sA[WS1_BH];           // 50,688 B
  __shared__ __bf16 sB[WS2_BH];           // 84,480 B (single buffer)

  // stage A (once) and B for i=0 (dy=-20)
  {
    const uint4* g = (const uint4*)(ws1 + (size_t)(b * 64 + h) * WS1_BH);
    uint4* d = (uint4*)sA;
    for (int j = t; j < WS1_BH / 8; j += 384) d[j] = g[j];   // 3168 chunks
  }
  bool vcur = (h - 20 >= 0);
  if (vcur) {
    const uint4* g = (const uint4*)(ws2 + (size_t)(b * 64 + h - 20) * WS2_BH);
    uint4* d = (uint4*)sB;
    for (int j = t; j < WS2_BH / 8; j += 384) d[j] = g[j];   // 5280 chunks
  }
  __syncthreads();

  const __bf16* pA  = sA + (size_t)(rr * NU + u0 + col) * CP + quad * 8;
  const __bf16* pB0 = sB + (size_t)(rr * NQ + u0 +  0 + col) * CP + quad * 8;
  const __bf16* pB1 = pB0 + 16 * CP;
  const __bf16* pB2 = pB1 + 16 * CP;
  const float scale = 1.0f / 256.0f;

  uint4 regs[14];
  for (int i = 0; i < 21; ++i) {
    // issue global loads for dy(i+1) -- in flight during compute
    bool vnxt = false;
    if (i < 20) {
      int hs = h + 2 * (i + 1) - 20;
      vnxt = (hs >= 0 && hs < H_);
      if (vnxt) {
        const uint4* g = (const uint4*)(ws2 + (size_t)(b * 64 + hs) * WS2_BH);
#pragma unroll
        for (int j = 0; j < 14; ++j) {
          int idx = t + j * 384;
          if (idx < WS2_BH / 8) regs[j] = g[idx];
        }
      }
    }

    f32x4 z = {0.f, 0.f, 0.f, 0.f};
    f32x4 acc0 = z, acc1 = z, acc2 = z;
    if (vcur) {
#pragma unroll
      for (int s = 0; s < 8; ++s) {
        bf16x8 a  = *(const bf16x8*)(pA  + 32 * s);
        bf16x8 b0 = *(const bf16x8*)(pB0 + 32 * s);
        bf16x8 b1 = *(const bf16x8*)(pB1 + 32 * s);
        bf16x8 b2 = *(const bf16x8*)(pB2 + 32 * s);
        acc0 = __builtin_amdgcn_mfma_f32_16x16x32_bf16(a, b0, acc0, 0, 0, 0);
        acc1 = __builtin_amdgcn_mfma_f32_16x16x32_bf16(a, b1, acc1, 0, 0, 0);
        acc2 = __builtin_amdgcn_mfma_f32_16x16x32_bf16(a, b2, acc2, 0, 0, 0);
      }
    }

    // store: D row = u-offset = quad*4+reg, D col = v-offset; ix = v-u+10
    f32x4 at[3] = {acc0, acc1, acc2};
#pragma unroll
    for (int tt = 0; tt < 3; ++tt) {
#pragma unroll
      for (int reg = 0; reg < 4; ++reg) {
        int du = quad * 4 + reg;
        int ix = (tt - 1) * 16 + col - du + 10;
        if (ix >= 0 && ix < 21) {
          int w = 2 * (u0 + du) + rr;
          out[((size_t)(b * 441 + i * 21 + ix) * H_ + h) * W_ + w] = at[tt][reg] * scale;
        }
      }
    }

    __syncthreads();   // all waves done reading sB before overwrite
    if (i < 20 && vnxt) {
      uint4* d = (uint4*)sB;
#pragma unroll
      for (int j = 0; j < 14; ++j) {
        int idx = t + j * 384;
        if (idx < WS2_BH / 8) d[idx] = regs[j];
      }
    }
    vcur = vnxt;
    __syncthreads();   // new sB visible
  }
}

extern "C" void kernel_launch(void* const* d_in, const int* in_sizes, int n_in,
                              void* d_out, int out_size, void* d_ws, size_t ws_size,
                              hipStream_t stream) {
  const float* in1 = (const float*)d_in[0];
  const float* in2 = (const float*)d_in[1];
  float* out = (float*)d_out;
  __bf16* ws1 = (__bf16*)d_ws;                         // 512 * 25344 elems
  __bf16* ws2 = ws1 + (size_t)512 * WS1_BH;            // 512 * 42240 elems

  pack_kernel<<<512, 256, 0, stream>>>(in1, in2, ws1, ws2);
  corr_mfma<<<512, 384, 0, stream>>>(ws1, ws2, out);
}

// Round 3
// 381.179 us; speedup vs baseline: 5.8391x; 1.3258x over previous
//
#include <hip/hip_runtime.h>

// FlowNetC correlation, bf16 MFMA banded-GEMM, v3.
// out[b, iy*21+ix, h, w] = (1/256) sum_c in1[b,c,h,w] * in2[b,c,h+dy,w+dx]
// Parity split w=2u+r, w'=2v+r, v=u+ix-10 -> banded Gram per (b, h-pair, r).
// Pack: BOTH inputs -> ws[inp][b][h][row=r*48+u][c(pad 264)] bf16 (50.7 KB/row).
// Compute: block=(b,h2) where h2 indexes the in2 row. sB staged once (guard
// zeros for v<0, v>=48 written in LDS); A rows h=h2-dy streamed over the 21 dy
// with a register-prefetch pipeline. Epilogue transposes MFMA C-layout through
// LDS tile sO[21][100] and stores coalesced float4. Out rows whose in2 source
// row is out-of-image are zero-filled by block h2==h (exact partition).

#define B_    8
#define C_    256
#define H_    64
#define W_    96
#define CP    264            // padded c row (528 B; 132 dw = 4 mod 32)
#define WSROW (96 * CP)      // 25344 bf16 = 50688 B per (input,b,h)

typedef __bf16 bf16x8 __attribute__((ext_vector_type(8)));
typedef __bf16 bf16x4 __attribute__((ext_vector_type(4)));
typedef float  f32x4  __attribute__((ext_vector_type(4)));

// ---------------- Phase 1: pack fp32 -> bf16, layout [row=r*48+u][c]
__global__ __launch_bounds__(256) void pack_kernel(
    const float* __restrict__ in1, const float* __restrict__ in2,
    __bf16* __restrict__ ws) {
  const int id = blockIdx.x;            // [inp(2)][b(8)][h(64)]
  const float* src = (id >> 9) ? in2 : in1;
  const int bh = id & 511;
  const int b = bh >> 6, h = bh & 63;
  __bf16* dst = ws + (size_t)id * WSROW;
  const size_t base = (size_t)b * C_ * H_ * W_ + (size_t)h * W_;
  const int t = threadIdx.x;

  __shared__ float sT[64][97];

  for (int c0 = 0; c0 < C_; c0 += 64) {
    __syncthreads();
    for (int idx = t; idx < 1536; idx += 256) {        // 64 c x 24 float4
      int cc = idx / 24, w4 = idx % 24;
      float4 v = *(const float4*)(src + base + (size_t)(c0 + cc) * H_ * W_ + w4 * 4);
      sT[cc][w4 * 4 + 0] = v.x; sT[cc][w4 * 4 + 1] = v.y;
      sT[cc][w4 * 4 + 2] = v.z; sT[cc][w4 * 4 + 3] = v.w;
    }
    __syncthreads();
    for (int idx = t; idx < 1536; idx += 256) {        // 96 rows x 16 bf16x4
      int ru = idx >> 4, ci = idx & 15;
      int r = (ru >= 48) ? 1 : 0;
      int u = ru - r * 48;
      int x = 2 * u + r;
      bf16x4 o;
      o[0] = (__bf16)sT[4 * ci + 0][x];
      o[1] = (__bf16)sT[4 * ci + 1][x];
      o[2] = (__bf16)sT[4 * ci + 2][x];
      o[3] = (__bf16)sT[4 * ci + 3][x];
      *(bf16x4*)(dst + (size_t)ru * CP + c0 + 4 * ci) = o;
    }
  }
}

// ---------------- Phase 2: MFMA band-GEMM, block = (b, h2 = in2 row)
__global__ __launch_bounds__(384) void corr_mfma(
    const __bf16* __restrict__ ws, float* __restrict__ out) {
  const int b = blockIdx.x >> 6;
  const int h2 = blockIdx.x & 63;
  const int t = threadIdx.x;
  const int wave = t >> 6, lane = t & 63;
  const int rr = wave & 1;               // parity
  const int u0 = (wave >> 1) << 4;       // u-tile base: 0,16,32
  const int col = lane & 15, quad = lane >> 4;
  const float scale = 1.0f / 256.0f;

  const __bf16* ws1 = ws;
  const __bf16* ws2 = ws + (size_t)512 * WSROW;

  __shared__ __bf16 sA[WSROW];           // 50688 B
  __shared__ __bf16 sB[2 * 80 * CP];     // 84480 B (q = v+16, v in [-16,64))
  __shared__ float  sO[21][100];         // 8400 B epilogue tile

  // Zero out rows (b, i*21+ix, h2, :) whose in2 source row h2+dy is OOB.
  {
    const float4 z4 = {0.f, 0.f, 0.f, 0.f};
    for (int i = 0; i < 21; ++i) {
      int hh = h2 + 2 * i - 20;
      if (hh < 0 || hh >= H_) {
        for (int idx = t; idx < 504; idx += 384) {
          int ix = idx / 24, w4 = idx % 24;
          *(float4*)(out + ((size_t)(b * 441 + i * 21 + ix) * H_ + h2) * W_ + w4 * 4) = z4;
        }
      }
    }
  }

  // Stage sB: guards (q<16 or q>=64) = 0, middle from ws2(b,h2).
  {
    const uint4 z = {0, 0, 0, 0};
    uint4* d = (uint4*)sB;
    for (int idx = t; idx < 2112; idx += 384) {        // 64 guard rows x 33
      int grow = idx / 33, c4 = idx % 33;
      int r = grow >> 5, qq = grow & 31;
      int q = (qq < 16) ? qq : qq + 48;
      d[(r * 80 + q) * 33 + c4] = z;
    }
    const uint4* g = (const uint4*)(ws2 + (size_t)blockIdx.x * WSROW);
    for (int idx = t; idx < 3168; idx += 384) {        // 96 rows x 33
      int srow = idx / 33, c4 = idx % 33;
      int r = (srow >= 48) ? 1 : 0;
      int u = srow - r * 48;
      d[(r * 80 + 16 + u) * 33 + c4] = g[idx];
    }
  }

  // Valid dy range for this block: h = h2 - 2i + 20 in [0, 64)
  const int i_lo = max(0, (h2 - 42) >> 1);
  const int i_hi = min(20, (h2 + 20) >> 1);

  // Stage first A row
  {
    int h = h2 - 2 * i_lo + 20;
    const uint4* g = (const uint4*)(ws1 + (size_t)(b * 64 + h) * WSROW);
    uint4* d = (uint4*)sA;
    for (int idx = t; idx < 3168; idx += 384) d[idx] = g[idx];
  }
  __syncthreads();

  const __bf16* pA  = sA + (size_t)(rr * 48 + u0 + col) * CP + quad * 8;
  const __bf16* pB0 = sB + (size_t)(rr * 80 + u0 + col) * CP + quad * 8;  // v=u0+col-16
  const __bf16* pB1 = pB0 + 16 * CP;
  const __bf16* pB2 = pB1 + 16 * CP;

  uint4 regs[9];
  for (int i = i_lo; i <= i_hi; ++i) {
    const bool pf = (i < i_hi);
    if (pf) {
      int hn = h2 - 2 * (i + 1) + 20;
      const uint4* g = (const uint4*)(ws1 + (size_t)(b * 64 + hn) * WSROW);
#pragma unroll
      for (int j = 0; j < 9; ++j) {
        int idx = t + j * 384;
        if (idx < 3168) regs[j] = g[idx];
      }
    }

    f32x4 acc0 = {0.f, 0.f, 0.f, 0.f};
    f32x4 acc1 = acc0, acc2 = acc0;
#pragma unroll
    for (int s = 0; s < 8; ++s) {
      bf16x8 a  = *(const bf16x8*)(pA  + 32 * s);
      bf16x8 b0 = *(const bf16x8*)(pB0 + 32 * s);
      bf16x8 b1 = *(const bf16x8*)(pB1 + 32 * s);
      bf16x8 b2 = *(const bf16x8*)(pB2 + 32 * s);
      acc0 = __builtin_amdgcn_mfma_f32_16x16x32_bf16(a, b0, acc0, 0, 0, 0);
      acc1 = __builtin_amdgcn_mfma_f32_16x16x32_bf16(a, b1, acc1, 0, 0, 0);
      acc2 = __builtin_amdgcn_mfma_f32_16x16x32_bf16(a, b2, acc2, 0, 0, 0);
    }

    // Scatter C tiles into sO[ix][w] (D row=u-off=quad*4+reg, D col=v-off)
    f32x4 at[3] = {acc0, acc1, acc2};
#pragma unroll
    for (int tt = 0; tt < 3; ++tt) {
#pragma unroll
      for (int reg = 0; reg < 4; ++reg) {
        int du = quad * 4 + reg;
        int ix = (tt - 1) * 16 + col - du + 10;
        if (ix >= 0 && ix < 21) {
          sO[ix][2 * (u0 + du) + rr] = at[tt][reg] * scale;
        }
      }
    }

    __syncthreads();   // scatter done + sA fragment reads done

    if (pf) {
      uint4* d = (uint4*)sA;
#pragma unroll
      for (int j = 0; j < 9; ++j) {
        int idx = t + j * 384;
        if (idx < 3168) d[idx] = regs[j];
      }
    }

    // Coalesced store of the [21][96] tile
    {
      int h = h2 - 2 * i + 20;
      for (int idx = t; idx < 504; idx += 384) {
        int ix = idx / 24, w4 = idx % 24;
        float4 v = *(const float4*)(&sO[ix][w4 * 4]);
        *(float4*)(out + ((size_t)(b * 441 + i * 21 + ix) * H_ + h) * W_ + w4 * 4) = v;
      }
    }

    __syncthreads();   // sA write visible; sO gather done before next scatter
  }
}

extern "C" void kernel_launch(void* const* d_in, const int* in_sizes, int n_in,
                              void* d_out, int out_size, void* d_ws, size_t ws_size,
                              hipStream_t stream) {
  const float* in1 = (const float*)d_in[0];
  const float* in2 = (const float*)d_in[1];
  float* out = (float*)d_out;
  __bf16* ws = (__bf16*)d_ws;    // 1024 * 25344 bf16 = 51.9 MB

  pack_kernel<<<1024, 256, 0, stream>>>(in1, in2, ws);
  corr_mfma<<<512, 384, 0, stream>>>(ws, out);
}

// Round 5
// 246.495 us; speedup vs baseline: 9.0296x; 1.5464x over previous
//
#include <hip/hip_runtime.h>
#include <stdint.h>

// FlowNetC correlation, bf16 MFMA banded-GEMM, v4.1 (compile fix of v4).
// out[b, iy*21+ix, h, w] = (1/256) sum_c in1[b,c,h,w] * in2[b,c,h+dy,w+dx]
// Parity split w=2u+r, w'=2v+r, v=u+ix-10 -> banded Gram per (b, h-pair, r).
// ws layout (both inputs): [inp][b][h][row=r*48+u][c pad 264] bf16, 50688 B/row.
// corr: block=(b,h2=in2 row). B-row fragments loaded ONCE into registers
// (guard zeros by predication). A rows h=h2-dy streamed via async
// global_load_lds (width 16) into double-buffered sA -> no staging VGPRs, no
// spills. One barrier per iter (its vmcnt(0) drain is the buffer handoff).
// Epilogue via double-buffered sO tile -> coalesced float4 stores.

#define CP    264            // padded c row (528 B; 132 dw = 4 mod 32: 2-way free)
#define WSROW (96 * CP)      // 25344 bf16 = 50688 B per (input,b,h)

typedef __bf16 bf16x8 __attribute__((ext_vector_type(8)));
typedef float  f32x4  __attribute__((ext_vector_type(4)));

__device__ __forceinline__ void gl2lds16(const void* gptr, void* lptr) {
  auto g = (const __attribute__((address_space(1))) uint32_t*)
      reinterpret_cast<uintptr_t>(gptr);
  auto l = (__attribute__((address_space(3))) uint32_t*)
      reinterpret_cast<uintptr_t>(lptr);
  __builtin_amdgcn_global_load_lds(g, l, 16, 0, 0);
}

// ---------------- Phase 1: pack fp32 -> bf16, direct (no LDS)
// grid 1024 = [inp(2)][b(8)][h(64)], block 384 = cig(4) x x(96)
__global__ __launch_bounds__(384) void pack_kernel(
    const float* __restrict__ in1, const float* __restrict__ in2,
    __bf16* __restrict__ ws) {
  const int id = blockIdx.x;
  const float* src = (id >> 9) ? in2 : in1;
  const int bh = id & 511;
  const int b = bh >> 6, h = bh & 63;
  const int t = threadIdx.x;
  const int x = t % 96, cig = t / 96;           // cig in [0,4)
  const int row = (x & 1) * 48 + (x >> 1);      // parity-major row index

  const size_t sbase = (size_t)b * (256 * 64 * 96) + (size_t)h * 96 + x;
  __bf16* dst = ws + (size_t)id * WSROW + (size_t)row * CP;

#pragma unroll
  for (int g = 0; g < 8; ++g) {                 // c-chunks of 32
    const int cb = g * 32 + cig * 8;
    float v[8];
#pragma unroll
    for (int k = 0; k < 8; ++k)
      v[k] = src[sbase + (size_t)(cb + k) * (64 * 96)];
    bf16x8 o;
#pragma unroll
    for (int k = 0; k < 8; ++k) o[k] = (__bf16)v[k];
    *(bf16x8*)(dst + cb) = o;
  }
}

// ---------------- Phase 2: MFMA band-GEMM, block = (b, h2 = in2 row)
__global__ __launch_bounds__(384, 1) void corr_mfma(
    const __bf16* __restrict__ ws, float* __restrict__ out) {
  const int b = blockIdx.x >> 6;
  const int h2 = blockIdx.x & 63;
  const int t = threadIdx.x;
  const int wave = t >> 6, lane = t & 63;
  const int rr = wave & 1;               // parity
  const int u0 = (wave >> 1) << 4;       // u-tile base: 0,16,32
  const int col = lane & 15, quad = lane >> 4;
  const float scale = 1.0f / 256.0f;

  const __bf16* ws1 = ws;
  const __bf16* ws2 = ws + (size_t)512 * WSROW;

  __shared__ __bf16 sA[2][WSROW];        // 2 x 50688 B
  __shared__ float  sO[2][21][100];      // 2 x 8400 B

  // Zero-fill out rows whose in2 source row h2+dy is out of image.
  {
    const float4 z4 = {0.f, 0.f, 0.f, 0.f};
    for (int i = 0; i < 21; ++i) {
      int hh = h2 + 2 * i - 20;
      if (hh < 0 || hh >= 64) {
        for (int idx = t; idx < 504; idx += 384) {
          int ix = idx / 24, w4 = idx % 24;
          *(float4*)(out + ((size_t)(b * 441 + i * 21 + ix) * 64 + h2) * 96 + w4 * 4) = z4;
        }
      }
    }
  }

  // Valid dy range: h = h2 - 2i + 20 in [0, 64)
  const int i_lo = max(0, (h2 - 42) >> 1);
  const int i_hi = min(20, (h2 + 20) >> 1);

  // 1) DMA B row (b,h2) -> sA[0]
  {
    const char* g = (const char*)(ws2 + (size_t)blockIdx.x * WSROW);
    char* l = (char*)&sA[0][0];
#pragma unroll
    for (int j = 0; j < 9; ++j) {
      int idx = t + j * 384;
      if (idx < 3168) gl2lds16(g + idx * 16, l + idx * 16);
    }
  }
  __syncthreads();                       // sA[0] ready

  // 2) DMA A(i_lo) -> sA[1], in flight while we read B fragments
  {
    int h = h2 - 2 * i_lo + 20;
    const char* g = (const char*)(ws1 + (size_t)(b * 64 + h) * WSROW);
    char* l = (char*)&sA[1][0];
#pragma unroll
    for (int j = 0; j < 9; ++j) {
      int idx = t + j * 384;
      if (idx < 3168) gl2lds16(g + idx * 16, l + idx * 16);
    }
  }

  // 3) B fragments -> registers; v outside [0,48) is zero (image pad)
  bf16x8 bfrag[3][8];
#pragma unroll
  for (int tt = 0; tt < 3; ++tt) {
    int v = u0 + 16 * (tt - 1) + col;
    bool ok = (v >= 0 && v < 48);
    const __bf16* p = &sA[0][(rr * 48 + (ok ? v : 0)) * CP + quad * 8];
#pragma unroll
    for (int s = 0; s < 8; ++s) {
      bf16x8 val = *(const bf16x8*)(p + 32 * s);
      if (!ok) {
#pragma unroll
        for (int k = 0; k < 8; ++k) val[k] = (__bf16)0.0f;
      }
      bfrag[tt][s] = val;
    }
  }
  __syncthreads();   // all waves done with sA[0]; vmcnt drained -> sA[1] ready

  // main loop: iter i reads sA[(i - i_lo + 1) & 1]
  for (int i = i_lo; i <= i_hi; ++i) {
    const int buf = (i - i_lo + 1) & 1;
    const int ob  = (i - i_lo) & 1;

    if (i < i_hi) {                      // DMA next A row into the other buffer
      int hn = h2 - 2 * (i + 1) + 20;
      const char* g = (const char*)(ws1 + (size_t)(b * 64 + hn) * WSROW);
      char* l = (char*)&sA[buf ^ 1][0];
#pragma unroll
      for (int j = 0; j < 9; ++j) {
        int idx = t + j * 384;
        if (idx < 3168) gl2lds16(g + idx * 16, l + idx * 16);
      }
    }

    f32x4 acc0 = {0.f, 0.f, 0.f, 0.f};
    f32x4 acc1 = acc0, acc2 = acc0;
    const __bf16* pA = &sA[buf][(rr * 48 + u0 + col) * CP + quad * 8];
#pragma unroll
    for (int s = 0; s < 8; ++s) {
      bf16x8 a = *(const bf16x8*)(pA + 32 * s);
      acc0 = __builtin_amdgcn_mfma_f32_16x16x32_bf16(a, bfrag[0][s], acc0, 0, 0, 0);
      acc1 = __builtin_amdgcn_mfma_f32_16x16x32_bf16(a, bfrag[1][s], acc1, 0, 0, 0);
      acc2 = __builtin_amdgcn_mfma_f32_16x16x32_bf16(a, bfrag[2][s], acc2, 0, 0, 0);
    }

    // Scatter C tiles into sO[ob] (D row = u-off = quad*4+reg, D col = v-off)
    f32x4 at[3] = {acc0, acc1, acc2};
#pragma unroll
    for (int tt = 0; tt < 3; ++tt) {
#pragma unroll
      for (int reg = 0; reg < 4; ++reg) {
        int du = quad * 4 + reg;
        int ix = (tt - 1) * 16 + col - du + 10;
        if (ix >= 0 && ix < 21)
          sO[ob][ix][2 * (u0 + du) + rr] = at[tt][reg] * scale;
      }
    }

    __syncthreads();   // scatter + A-reads done; DMA(i+1) drained (vmcnt 0)

    // Coalesced store of the [21][96] tile
    {
      int h = h2 - 2 * i + 20;
      for (int idx = t; idx < 504; idx += 384) {
        int ixx = idx / 24, w4 = idx % 24;
        float4 v = *(const float4*)(&sO[ob][ixx][w4 * 4]);
        *(float4*)(out + ((size_t)(b * 441 + i * 21 + ixx) * 64 + h) * 96 + w4 * 4) = v;
      }
    }
  }
}

extern "C" void kernel_launch(void* const* d_in, const int* in_sizes, int n_in,
                              void* d_out, int out_size, void* d_ws, size_t ws_size,
                              hipStream_t stream) {
  const float* in1 = (const float*)d_in[0];
  const float* in2 = (const float*)d_in[1];
  float* out = (float*)d_out;
  __bf16* ws = (__bf16*)d_ws;    // 1024 * 25344 bf16 = 51.9 MB

  pack_kernel<<<1024, 384, 0, stream>>>(in1, in2, ws);
  corr_mfma<<<512, 384, 0, stream>>>(ws, out);
}